// Round 5
// baseline (321.158 us; speedup 1.0000x reference)
//
#include <hip/hip_runtime.h>

// ============================================================================
// STDP plasticity — r17: r9 GEMM + distributed last-arriver merge (256 winners).
// Ledger: r9 199.3 (gemm_split 76/904TF + merge2 11). r14 8-phase flight-7:
// gemm 68 but merge4 16, total 200.1 (tie). r15 even-reads 71 (refuted).
// r16 fused merge on 64 blocks: +122us — RULE: BW-bound tail time =
// bytes/(participating CUs x 25 GB/s); 64 CUs for 100MB = 63us serial.
// r17: keep r9's proven 128²/split-K=2 K-loop; fuse merge via per-tile ticket:
// both z-siblings (same XCD by swizzle) write their partial + threadfence +
// atomicAdd; second arriver (256 winners, one per CU on average) computes
// scale from sp and merges at fragment coords with own acc in regs:
// 50MB / 256 CUs = ~8us tail vs 11us merge kernel + launch. Traffic 100->84MB.
// Predict: gemm_fz 82-90, no merge dispatch, total ~185-193.
// Closed branches: fused epi spin-flags (r4 +126), coop-sync (r8), BK=32@128²
// (r7), fused gemm+merge single-kernel (r10/r11 +3), stage split (r12 +4),
// 8ph flight-2 (r13 +10), even-reads (r15 +3), 64-block fused merge (r16 +110).
// ============================================================================

constexpr int TB = 16;        // batch
constexpr int NP = 2048;      // pre neurons
constexpr int NQ = 2048;      // post neurons
constexpr int TT = 256;       // timesteps
constexpr int KH = TB * TT;   // 4096, half-K
constexpr int KT = 2 * KH;    // 8192, total contraction length

typedef unsigned short ushort_t;
typedef __attribute__((ext_vector_type(8))) __bf16 bf16x8;
typedef __attribute__((ext_vector_type(4))) float f32x4;

// bf16 round-to-nearest-even, as uint (inputs finite)
__device__ __forceinline__ unsigned bf1(float f) {
    unsigned u = __builtin_bit_cast(unsigned, f);
    return (u + 0x7FFFu + ((u >> 16) & 1u)) >> 16;
}
__device__ __forceinline__ unsigned pack2(float lo, float hi) {
    return bf1(lo) | (bf1(hi) << 16);
}
__device__ __forceinline__ unsigned spk2(float a, float b) {
    return ((a != 0.f) ? 0x3F80u : 0u) | ((b != 0.f) ? 0x3F800000u : 0u);
}

// Decay powers
constexpr float DF1 = 0.95122942450071400910f;            // exp(-0.05)
constexpr float DF2 = DF1 * DF1;
constexpr float DF4 = DF2 * DF2;
constexpr float DF8 = DF4 * DF4;
constexpr float DF16 = DF8 * DF8;
constexpr float DF32 = DF16 * DF16;
constexpr float DF64 = DF32 * DF32;

constexpr float DX1 = 0.99014786386058731819f;            // exp(-1/101)
constexpr float DX2 = DX1 * DX1;
constexpr float DX4 = DX2 * DX2;
constexpr float DX8 = DX4 * DX4;
constexpr float DX16 = DX8 * DX8;
constexpr float DX32 = DX16 * DX16;
constexpr float DX64 = DX32 * DX32;

template <int K>
__device__ __forceinline__ float seg_step(float b, float pw, int sl) {
    float t = __shfl_up(b, K, 64);
    return (sl >= K) ? fmaf(pw, t, b) : b;
}
__device__ __forceinline__ float scan16(float c, float p1, float p2, float p4,
                                        float p8, int sl) {
    c = seg_step<1>(c, p1, sl);
    c = seg_step<2>(c, p2, sl);
    c = seg_step<4>(c, p4, sl);
    c = seg_step<8>(c, p8, sl);
    return c;
}
__device__ __forceinline__ float fold4(float4 u, float d) {
    float C = d * u.x;
    C = d * (C + u.y); C = d * (C + u.z); C = d * (C + u.w);
    return C;
}
__device__ __forceinline__ float4 expand4(float x, float4 u, float d) {
    float4 t;
    t.x = x; x = d * (x + u.x);
    t.y = x; x = d * (x + u.y);
    t.z = x; x = d * (x + u.z);
    t.w = x;
    return t;
}

// ---------------------------------------------------------------------------
// Stage 1 (r9-proven): slot-coalesced traces -> bf16 A/B panels.
// Block 0 also zeroes the 256 per-tile merge counters (graph-replay-safe).
// ---------------------------------------------------------------------------
__global__ __launch_bounds__(256) void stage_traces(
    const float* __restrict__ pre, const float* __restrict__ post,
    const float* __restrict__ mApP, const float* __restrict__ mAmP,
    ushort_t* __restrict__ Ab, ushort_t* __restrict__ Bb,
    float* __restrict__ partials, int* __restrict__ cnt)
{
    const int tid  = threadIdx.x;
    if (blockIdx.x == 0) cnt[tid] = 0;     // 256 counters, 256 threads

    const int lane = tid & 63;
    const int wv   = tid >> 6;
    const int sl   = lane & 15;
    const int rowg = blockIdx.x * 16 + wv * 4 + (lane >> 4);   // 0..65535
    const bool isPre = rowg < TB * NP;                         // block-uniform
    const int m = isPre ? rowg : rowg - TB * NP;
    const int b = m >> 11;
    const int r = m & 2047;

    const float4* srcRow = (const float4*)((isPre ? pre : post) + (size_t)m * TT);
    const float4 u0 = srcRow[sl];          // slot 0: t = 4sl..4sl+3
    const float4 u1 = srcRow[16 + sl];     // slot 1
    const float4 u2 = srcRow[32 + sl];     // slot 2
    const float4 u3 = srcRow[48 + sl];     // slot 3

    float cnt_s = ((u0.x + u0.y) + (u0.z + u0.w)) + ((u1.x + u1.y) + (u1.z + u1.w))
                + ((u2.x + u2.y) + (u2.z + u2.w)) + ((u3.x + u3.y) + (u3.z + u3.w));

    const int hi = lane | 15;

    // ---- fast-decay trace: per-slot scans + cross-slot carry ----
    float bf0 = scan16(fold4(u0, DF1), DF4, DF8, DF16, DF32, sl);
    float bf1_ = scan16(fold4(u1, DF1), DF4, DF8, DF16, DF32, sl);
    float bf2 = scan16(fold4(u2, DF1), DF4, DF8, DF16, DF32, sl);
    float bf3 = scan16(fold4(u3, DF1), DF4, DF8, DF16, DF32, sl);
    const float Tf0 = __shfl(bf0, hi, 64);
    const float Tf1 = __shfl(bf1_, hi, 64);
    const float Tf2 = __shfl(bf2, hi, 64);
    const float Xf1 = Tf0;
    const float Xf2 = fmaf(DF64, Xf1, Tf1);
    const float Xf3 = fmaf(DF64, Xf2, Tf2);
    float ef0 = __shfl_up(bf0, 1, 64);
    float ef1 = __shfl_up(bf1_, 1, 64);
    float ef2 = __shfl_up(bf2, 1, 64);
    float ef3 = __shfl_up(bf3, 1, 64);
    if (sl == 0) { ef0 = 0.f; ef1 = 0.f; ef2 = 0.f; ef3 = 0.f; }
    float pf = 1.f;
    if (sl & 1) pf *= DF4;
    if (sl & 2) pf *= DF8;
    if (sl & 4) pf *= DF16;
    if (sl & 8) pf *= DF32;
    const float4 t0 = expand4(ef0,                 u0, DF1);
    const float4 t1 = expand4(fmaf(pf, Xf1, ef1),  u1, DF1);
    const float4 t2 = expand4(fmaf(pf, Xf2, ef2),  u2, DF1);
    const float4 t3 = expand4(fmaf(pf, Xf3, ef3),  u3, DF1);

    ushort_t* oA = (isPre ? Ab : Bb) + (size_t)r * KT + b * TT + 4 * sl;

    if (isPre) {
        *(uint2*)(oA)            = uint2{pack2(t0.x, t0.y), pack2(t0.z, t0.w)};
        *(uint2*)(oA + 64)       = uint2{pack2(t1.x, t1.y), pack2(t1.z, t1.w)};
        *(uint2*)(oA + 128)      = uint2{pack2(t2.x, t2.y), pack2(t2.z, t2.w)};
        *(uint2*)(oA + 192)      = uint2{pack2(t3.x, t3.y), pack2(t3.z, t3.w)};
        *(uint2*)(oA + KH)       = uint2{spk2(u0.x, u0.y), spk2(u0.z, u0.w)};
        *(uint2*)(oA + KH + 64)  = uint2{spk2(u1.x, u1.y), spk2(u1.z, u1.w)};
        *(uint2*)(oA + KH + 128) = uint2{spk2(u2.x, u2.y), spk2(u2.z, u2.w)};
        *(uint2*)(oA + KH + 192) = uint2{spk2(u3.x, u3.y), spk2(u3.z, u3.w)};
    } else {
        // ---- slow (triplet) trace ----
        float bx0 = scan16(fold4(u0, DX1), DX4, DX8, DX16, DX32, sl);
        float bx1 = scan16(fold4(u1, DX1), DX4, DX8, DX16, DX32, sl);
        float bx2 = scan16(fold4(u2, DX1), DX4, DX8, DX16, DX32, sl);
        float bx3 = scan16(fold4(u3, DX1), DX4, DX8, DX16, DX32, sl);
        const float Tx0 = __shfl(bx0, hi, 64);
        const float Tx1 = __shfl(bx1, hi, 64);
        const float Tx2 = __shfl(bx2, hi, 64);
        const float Xx1 = Tx0;
        const float Xx2 = fmaf(DX64, Xx1, Tx1);
        const float Xx3 = fmaf(DX64, Xx2, Tx2);
        float ex0 = __shfl_up(bx0, 1, 64);
        float ex1 = __shfl_up(bx1, 1, 64);
        float ex2 = __shfl_up(bx2, 1, 64);
        float ex3 = __shfl_up(bx3, 1, 64);
        if (sl == 0) { ex0 = 0.f; ex1 = 0.f; ex2 = 0.f; ex3 = 0.f; }
        float px = 1.f;
        if (sl & 1) px *= DX4;
        if (sl & 2) px *= DX8;
        if (sl & 4) px *= DX16;
        if (sl & 8) px *= DX32;
        const float4 w0 = expand4(ex0,                u0, DX1);
        const float4 w1 = expand4(fmaf(px, Xx1, ex1), u1, DX1);
        const float4 w2 = expand4(fmaf(px, Xx2, ex2), u2, DX1);
        const float4 w3 = expand4(fmaf(px, Xx3, ex3), u3, DX1);

        const float Ap = *mApP;
        const float Am = *mAmP;
        auto av2 = [&](float sa, float ta, float sb, float tb) -> unsigned {
            unsigned lo = (sa != 0.f) ? bf1(fmaf(0.0065f, ta, Ap)) : 0u;
            unsigned hi2 = (sb != 0.f) ? bf1(fmaf(0.0065f, tb, Ap)) : 0u;
            return lo | (hi2 << 16);
        };
        *(uint2*)(oA)       = uint2{av2(u0.x, w0.x, u0.y, w0.y), av2(u0.z, w0.z, u0.w, w0.w)};
        *(uint2*)(oA + 64)  = uint2{av2(u1.x, w1.x, u1.y, w1.y), av2(u1.z, w1.z, u1.w, w1.w)};
        *(uint2*)(oA + 128) = uint2{av2(u2.x, w2.x, u2.y, w2.y), av2(u2.z, w2.z, u2.w, w2.w)};
        *(uint2*)(oA + 192) = uint2{av2(u3.x, w3.x, u3.y, w3.y), av2(u3.z, w3.z, u3.w, w3.w)};
        *(uint2*)(oA + KH)       = uint2{pack2(-Am * t0.x, -Am * t0.y), pack2(-Am * t0.z, -Am * t0.w)};
        *(uint2*)(oA + KH + 64)  = uint2{pack2(-Am * t1.x, -Am * t1.y), pack2(-Am * t1.z, -Am * t1.w)};
        *(uint2*)(oA + KH + 128) = uint2{pack2(-Am * t2.x, -Am * t2.y), pack2(-Am * t2.z, -Am * t2.w)};
        *(uint2*)(oA + KH + 192) = uint2{pack2(-Am * t3.x, -Am * t3.y), pack2(-Am * t3.z, -Am * t3.w)};
    }

    #pragma unroll
    for (int off = 32; off > 0; off >>= 1)
        cnt_s += __shfl_down(cnt_s, off, 64);
    __shared__ float wsum[4];
    if (lane == 0) wsum[wv] = cnt_s;
    __syncthreads();
    if (tid == 0)
        partials[blockIdx.x] = (wsum[0] + wsum[1]) + (wsum[2] + wsum[3]);
}

// ---------------------------------------------------------------------------
// async global->LDS, 16B per lane, wave-contiguous dest.
// ---------------------------------------------------------------------------
__device__ __forceinline__ void async16(const ushort_t* g, ushort_t* l) {
    __builtin_amdgcn_global_load_lds(
        (const __attribute__((address_space(1))) unsigned int*)g,
        (__attribute__((address_space(3))) unsigned int*)l,
        16, 0, 0);
}

// ---------------------------------------------------------------------------
// Stage 2 (K-loop = r9's proven gemm_split verbatim): 128² tiles, split-K=2,
// BK=64, dbuf prefetch, XCD swizzle (z-siblings differ only in id bit 3 ->
// SAME XCD -> sibling partial is L2-local). Fused distributed merge: both
// z-blocks write their partial, threadfence, ticket = atomicAdd(cnt[tile]).
// First arriver exits; second (256 winners, ~1/CU) computes scale from sp
// and writes clip(W + scale*(acc_regs + sibling_partial)) at its fragment
// coords. Tail = 50MB / (256 CU x 25 GB/s) ~ 8us (r16 rule).
// ---------------------------------------------------------------------------
__global__ __launch_bounds__(256, 2) void gemm_fz(
    const ushort_t* __restrict__ Ab, const ushort_t* __restrict__ Bb,
    const float* __restrict__ sp, const float* __restrict__ W,
    float* __restrict__ P0, float* __restrict__ P1,
    int* __restrict__ cnt, float* __restrict__ Out)
{
    __shared__ ushort_t Ls[2][128 * 64];
    __shared__ ushort_t Rs[2][128 * 64];
    __shared__ float red[4];
    __shared__ int tk;

    const int tid  = threadIdx.x;
    const int lane = tid & 63;
    const int wv   = tid >> 6;
    const int wr   = wv >> 1;
    const int wc   = wv & 1;
    const int quad = lane >> 4;
    const int m16  = lane & 15;

    const int id  = blockIdx.x;
    const int xcd = id & 7;
    const int j5  = id >> 3;
    const int z   = j5 & 1;
    const int t   = j5 >> 1;
    const int pt  = ((xcd >> 1) << 2) + (t >> 3);
    const int qt  = ((xcd & 1) << 3) + (t & 7);

    const int p0 = pt * 128;
    const int q0 = qt * 128;
    const int kbase = z * (KT / 2);
    const int ldsbase = wv * 512;

    const ushort_t* gaP[4];
    const ushort_t* gbP[4];
    #pragma unroll
    for (int rr = 0; rr < 4; ++rr) {
        const int c   = rr * 256 + tid;
        const int row = c >> 3;
        const int kk8 = (c & 7) ^ (row & 7);
        gaP[rr] = Ab + (size_t)(p0 + row) * KT + kbase + kk8 * 8;
        gbP[rr] = Bb + (size_t)(q0 + row) * KT + kbase + kk8 * 8;
    }

    f32x4 acc[4][4] = {};

    auto stageF = [&](int buf) {
        #pragma unroll
        for (int rr = 0; rr < 4; ++rr) {
            async16(gaP[rr], &Ls[buf][rr * 2048 + ldsbase]);
            async16(gbP[rr], &Rs[buf][rr * 2048 + ldsbase]);
            gaP[rr] += 64;
            gbP[rr] += 64;
        }
    };
    auto computeF = [&](int buf) {
        #pragma unroll
        for (int ks = 0; ks < 2; ++ks) {
            bf16x8 afl[4], bfr[4];
            #pragma unroll
            for (int i = 0; i < 4; ++i) {
                const int row  = wr * 64 + i * 16 + m16;
                const int slot = (ks * 4 + quad) ^ (row & 7);
                afl[i] = *(const bf16x8*)&Ls[buf][row * 64 + slot * 8];
            }
            #pragma unroll
            for (int jj = 0; jj < 4; ++jj) {
                const int row  = wc * 64 + jj * 16 + m16;
                const int slot = (ks * 4 + quad) ^ (row & 7);
                bfr[jj] = *(const bf16x8*)&Rs[buf][row * 64 + slot * 8];
            }
            #pragma unroll
            for (int i = 0; i < 4; ++i)
                #pragma unroll
                for (int jj = 0; jj < 4; ++jj)
                    acc[i][jj] = __builtin_amdgcn_mfma_f32_16x16x32_bf16(
                        afl[i], bfr[jj], acc[i][jj], 0, 0, 0);
        }
    };

    constexpr int NIT = (KT / 2) / 64;
    stageF(0);
    for (int kt2 = 0; kt2 < NIT / 2; ++kt2) {
        __syncthreads();
        stageF(1);
        computeF(0);
        __syncthreads();
        if (kt2 + 1 < NIT / 2)
            stageF(0);
        computeF(1);
    }

    // ---- fused epilogue ----
    // 1) write my partial (fragment coords)
    float* P = z ? P1 : P0;
    #pragma unroll
    for (int i = 0; i < 4; ++i) {
        const int prow = p0 + wr * 64 + i * 16 + quad * 4;
        #pragma unroll
        for (int jj = 0; jj < 4; ++jj) {
            const int qcol = q0 + wc * 64 + jj * 16 + m16;
            #pragma unroll
            for (int r2 = 0; r2 < 4; ++r2)
                P[(size_t)(prow + r2) * NQ + qcol] = acc[i][jj][r2];
        }
    }
    // 2) release + ticket
    __threadfence();
    if (tid == 0) tk = atomicAdd(&cnt[pt * 16 + qt], 1);
    __syncthreads();
    if (tk == 0) return;          // first arriver: done
    __threadfence();              // acquire: sibling's partial visible

    // 3) winner: scale from spike-count partials (L2-hot, 16KB)
    float v = 0.f;
    #pragma unroll
    for (int i = 0; i < 16; ++i) v += sp[tid + i * 256];
    #pragma unroll
    for (int off = 32; off > 0; off >>= 1)
        v += __shfl_down(v, off, 64);
    if (lane == 0) red[wv] = v;
    __syncthreads();
    const float s = (red[0] + red[1]) + (red[2] + red[3]);
    const float scale = sqrtf(0.1f / (s * (1.0f / 4096.0f) + 1e-6f));

    // 4) merge: own acc (regs) + sibling partial (same-XCD L2) + W -> Out
    const float* Ps = z ? P0 : P1;
    #pragma unroll
    for (int i = 0; i < 4; ++i) {
        const int prow = p0 + wr * 64 + i * 16 + quad * 4;
        #pragma unroll
        for (int jj = 0; jj < 4; ++jj) {
            const int qcol = q0 + wc * 64 + jj * 16 + m16;
            #pragma unroll
            for (int r2 = 0; r2 < 4; ++r2) {
                const size_t idx = (size_t)(prow + r2) * NQ + qcol;
                const float sum = acc[i][jj][r2] + Ps[idx];
                Out[idx] = fminf(fmaxf(fmaf(scale, sum, W[idx]), -2.f), 2.f);
            }
        }
    }
}

// ---------------------------------------------------------------------------
// FALLBACK (r9 verbatim): split-K=2 GEMM + merge kernel, if ws too small.
// ---------------------------------------------------------------------------
__global__ __launch_bounds__(256, 2) void gemm_split(
    const ushort_t* __restrict__ Ab, const ushort_t* __restrict__ Bb,
    const float* __restrict__ sp, float* __restrict__ scaleBuf,
    float* __restrict__ P0, float* __restrict__ P1)
{
    __shared__ ushort_t Ls[2][128 * 64];
    __shared__ ushort_t Rs[2][128 * 64];
    __shared__ float red[4];

    const int tid  = threadIdx.x;
    const int lane = tid & 63;
    const int wv   = tid >> 6;
    const int wr   = wv >> 1;
    const int wc   = wv & 1;
    const int quad = lane >> 4;
    const int m16  = lane & 15;

    if (blockIdx.x == 0) {
        float v = 0.f;
        #pragma unroll
        for (int i = 0; i < 16; ++i) v += sp[tid + i * 256];
        #pragma unroll
        for (int off = 32; off > 0; off >>= 1)
            v += __shfl_down(v, off, 64);
        if (lane == 0) red[wv] = v;
        __syncthreads();
        if (tid == 0) {
            float s = (red[0] + red[1]) + (red[2] + red[3]);
            scaleBuf[0] = sqrtf(0.1f / (s * (1.0f / 4096.0f) + 1e-6f));
        }
    }

    const int id  = blockIdx.x;
    const int xcd = id & 7;
    const int j5  = id >> 3;
    const int z   = j5 & 1;
    const int t   = j5 >> 1;
    const int pt  = ((xcd >> 1) << 2) + (t >> 3);
    const int qt  = ((xcd & 1) << 3) + (t & 7);

    const int p0 = pt * 128;
    const int q0 = qt * 128;
    const int kbase = z * (KT / 2);
    const int ldsbase = wv * 512;

    const ushort_t* gaP[4];
    const ushort_t* gbP[4];
    #pragma unroll
    for (int rr = 0; rr < 4; ++rr) {
        const int c   = rr * 256 + tid;
        const int row = c >> 3;
        const int kk8 = (c & 7) ^ (row & 7);
        gaP[rr] = Ab + (size_t)(p0 + row) * KT + kbase + kk8 * 8;
        gbP[rr] = Bb + (size_t)(q0 + row) * KT + kbase + kk8 * 8;
    }

    f32x4 acc[4][4] = {};

    auto stageF = [&](int buf) {
        #pragma unroll
        for (int rr = 0; rr < 4; ++rr) {
            async16(gaP[rr], &Ls[buf][rr * 2048 + ldsbase]);
            async16(gbP[rr], &Rs[buf][rr * 2048 + ldsbase]);
            gaP[rr] += 64;
            gbP[rr] += 64;
        }
    };
    auto computeF = [&](int buf) {
        #pragma unroll
        for (int ks = 0; ks < 2; ++ks) {
            bf16x8 afl[4], bfr[4];
            #pragma unroll
            for (int i = 0; i < 4; ++i) {
                const int row  = wr * 64 + i * 16 + m16;
                const int slot = (ks * 4 + quad) ^ (row & 7);
                afl[i] = *(const bf16x8*)&Ls[buf][row * 64 + slot * 8];
            }
            #pragma unroll
            for (int jj = 0; jj < 4; ++jj) {
                const int row  = wc * 64 + jj * 16 + m16;
                const int slot = (ks * 4 + quad) ^ (row & 7);
                bfr[jj] = *(const bf16x8*)&Rs[buf][row * 64 + slot * 8];
            }
            #pragma unroll
            for (int i = 0; i < 4; ++i)
                #pragma unroll
                for (int jj = 0; jj < 4; ++jj)
                    acc[i][jj] = __builtin_amdgcn_mfma_f32_16x16x32_bf16(
                        afl[i], bfr[jj], acc[i][jj], 0, 0, 0);
        }
    };

    constexpr int NIT = (KT / 2) / 64;
    stageF(0);
    for (int kt2 = 0; kt2 < NIT / 2; ++kt2) {
        __syncthreads();
        stageF(1);
        computeF(0);
        __syncthreads();
        if (kt2 + 1 < NIT / 2)
            stageF(0);
        computeF(1);
    }

    float* P = z ? P1 : P0;
    #pragma unroll
    for (int i = 0; i < 4; ++i) {
        const int prow = p0 + wr * 64 + i * 16 + quad * 4;
        #pragma unroll
        for (int jj = 0; jj < 4; ++jj) {
            const int qcol = q0 + wc * 64 + jj * 16 + m16;
            #pragma unroll
            for (int r2 = 0; r2 < 4; ++r2)
                P[(size_t)(prow + r2) * NQ + qcol] = acc[i][jj][r2];
        }
    }
}

__global__ __launch_bounds__(256) void merge_out2(
    const float* __restrict__ W, const float* __restrict__ P1,
    const float* __restrict__ scaleBuf, float* __restrict__ Out)
{
    const float scale = scaleBuf[0];
    const size_t i4 = (size_t)blockIdx.x * 256 + threadIdx.x;
    float4 w = ((const float4*)W)[i4];
    float4 a = ((const float4*)Out)[i4];
    float4 c = ((const float4*)P1)[i4];
    float4 o;
    o.x = fminf(fmaxf(fmaf(scale, a.x + c.x, w.x), -2.f), 2.f);
    o.y = fminf(fmaxf(fmaf(scale, a.y + c.y, w.y), -2.f), 2.f);
    o.z = fminf(fmaxf(fmaf(scale, a.z + c.z, w.z), -2.f), 2.f);
    o.w = fminf(fmaxf(fmaf(scale, a.w + c.w, w.w), -2.f), 2.f);
    ((float4*)Out)[i4] = o;
}

extern "C" void kernel_launch(void* const* d_in, const int* in_sizes, int n_in,
                              void* d_out, int out_size, void* d_ws, size_t ws_size,
                              hipStream_t stream) {
    const float* pre  = (const float*)d_in[0];
    const float* post = (const float*)d_in[1];
    const float* W    = (const float*)d_in[2];
    const float* mAp  = (const float*)d_in[3];
    const float* mAm  = (const float*)d_in[4];
    float* out = (float*)d_out;

    const size_t AB = (size_t)NP * KT * 2;   // 33.55 MB per panel
    const size_t PB = (size_t)NP * NQ * 4;   // 16.78 MB per partial

    char* ws = (char*)d_ws;
    float* partials = (float*)ws;                       // 16 KB (4096 slots)
    float* scaleBuf = (float*)(ws + 16384);             // fallback path only
    int*   cnt      = (int*)(ws + 20480);               // 256 tile counters
    ushort_t* Ab = (ushort_t*)(ws + 32768);
    ushort_t* Bb = (ushort_t*)(ws + 32768 + AB);
    float* Pa = (float*)(ws + 32768 + 2 * AB);          // z=0 partial
    float* Pb = (float*)(ws + 32768 + 2 * AB + PB);     // z=1 partial

    stage_traces<<<dim3((TB * NP + TB * NQ) / 16), dim3(256), 0, stream>>>(
        pre, post, mAp, mAm, Ab, Bb, partials, cnt);

    if (ws_size >= 32768 + 2 * AB + 2 * PB) {
        gemm_fz<<<dim3(512), dim3(256), 0, stream>>>(
            Ab, Bb, partials, W, Pa, Pb, cnt, out);
    } else {
        gemm_split<<<dim3(512), dim3(256), 0, stream>>>(
            Ab, Bb, partials, scaleBuf, out, Pa);
        merge_out2<<<dim3(NP * NQ / 1024), dim3(256), 0, stream>>>(
            W, Pa, scaleBuf, out);
    }
}

// Round 6
// 203.030 us; speedup vs baseline: 1.5818x; 1.5818x over previous
//
#include <hip/hip_runtime.h>

// ============================================================================
// STDP plasticity — r18: r9 gemm+merge verbatim + low-shfl stage_traces.
// Ledger: r9 199.3 (stage ~65, gemm_split 76/904TF, merge 11, ~36 fixed).
// GEMM branch closed: r13 flight-2 (78), r14 flight-7 (68 but merge4+launch
// eats it, total 200.1), r15 even-reads (71, refuted). Fusion branch CLOSED
// PERMANENTLY: r4 (+126), r16 (+110), r17 (+122) — __threadfence is a
// device-scope L2 writeback+invalidate on gfx950 (XCD L2s non-coherent);
// 512 blocks fencing mid-kernel destroys chip-wide L2 locality (r17 PMC:
// MfmaUtil 12.8%, HBM 795 GB/s during K-loop).
// r18 target: stage_traces runs ~65us for 134 MB ideal traffic (21us floor)
// -> not BW-bound; it issues ~23-46 ds_bpermute (__shfl) per row. New scheme:
// lane owns 16 CONTIGUOUS timesteps, fold16 -> ONE 16-lane scan (4 shfl_up)
// + 1 exclusive shfl = 5 shfl/trace (was ~23); expand fused with packing;
// 32B/lane uint4 writes. Same math/layout. Predict stage ~48, total ~186.
// Closed: r4/r16/r17 fence fusion, r7 BK=32, r8 coop, r10/r11 single-kernel,
// r12 stage split, r13/r14/r15 8-phase variants (gemm lever exhausted).
// ============================================================================

constexpr int TB = 16;        // batch
constexpr int NP = 2048;      // pre neurons
constexpr int NQ = 2048;      // post neurons
constexpr int TT = 256;       // timesteps
constexpr int KH = TB * TT;   // 4096, half-K
constexpr int KT = 2 * KH;    // 8192, total contraction length

typedef unsigned short ushort_t;
typedef __attribute__((ext_vector_type(8))) __bf16 bf16x8;
typedef __attribute__((ext_vector_type(4))) float f32x4;

// bf16 round-to-nearest-even, as uint (inputs finite)
__device__ __forceinline__ unsigned bf1(float f) {
    unsigned u = __builtin_bit_cast(unsigned, f);
    return (u + 0x7FFFu + ((u >> 16) & 1u)) >> 16;
}
__device__ __forceinline__ unsigned pack2(float lo, float hi) {
    return bf1(lo) | (bf1(hi) << 16);
}
__device__ __forceinline__ unsigned spk2(float a, float b) {
    return ((a != 0.f) ? 0x3F80u : 0u) | ((b != 0.f) ? 0x3F800000u : 0u);
}

// Decay powers
constexpr float DF1 = 0.95122942450071400910f;            // exp(-0.05)
constexpr float DF2 = DF1 * DF1;
constexpr float DF4 = DF2 * DF2;
constexpr float DF8 = DF4 * DF4;
constexpr float DF16 = DF8 * DF8;
constexpr float DF32 = DF16 * DF16;
constexpr float DF64 = DF32 * DF32;
constexpr float DF128 = DF64 * DF64;

constexpr float DX1 = 0.99014786386058731819f;            // exp(-1/101)
constexpr float DX2 = DX1 * DX1;
constexpr float DX4 = DX2 * DX2;
constexpr float DX8 = DX4 * DX4;
constexpr float DX16 = DX8 * DX8;
constexpr float DX32 = DX16 * DX16;
constexpr float DX64 = DX32 * DX32;
constexpr float DX128 = DX64 * DX64;

template <int K>
__device__ __forceinline__ float seg_step(float b, float pw, int sl) {
    float t = __shfl_up(b, K, 64);
    return (sl >= K) ? fmaf(pw, t, b) : b;
}
// 16-lane segmented inclusive scan; p1/p2/p4/p8 = per-block decay^{1,2,4,8}
__device__ __forceinline__ float scan16(float c, float p1, float p2, float p4,
                                        float p8, int sl) {
    c = seg_step<1>(c, p1, sl);
    c = seg_step<2>(c, p2, sl);
    c = seg_step<4>(c, p4, sl);
    c = seg_step<8>(c, p8, sl);
    return c;
}
// carry-through fold of a 4-block: x_out = d^4 x_in + sum d^{4-j} u_j
__device__ __forceinline__ float foldc4(float C, float4 u, float d) {
    C = d * (C + u.x); C = d * (C + u.y); C = d * (C + u.z); C = d * (C + u.w);
    return C;
}
// expand 4 trace values from carry x (trace at first elem), update carry
__device__ __forceinline__ float4 expand4c(float& x, float4 u, float d) {
    float4 t;
    t.x = x; x = d * (x + u.x);
    t.y = x; x = d * (x + u.y);
    t.z = x; x = d * (x + u.z);
    t.w = x; x = d * (x + u.w);
    return t;
}

// ---------------------------------------------------------------------------
// Stage 1 (r18): 16 lanes per (b,row); lane sl owns timesteps 16sl..16sl+15
// (contiguous). fold16 -> one 16-lane Kogge-Stone scan (d^16/32/64/128) ->
// exclusive carry -> serial expand fused with bf16 packing. 5 shfl per trace
// (was ~23). Writes 32B/lane contiguous uint4 pairs; layout identical to r9
// (column k = b*TT + t; traces in [0,KH), spikes/avals in [KH,KT)).
// ---------------------------------------------------------------------------
__global__ __launch_bounds__(256) void stage_traces(
    const float* __restrict__ pre, const float* __restrict__ post,
    const float* __restrict__ mApP, const float* __restrict__ mAmP,
    ushort_t* __restrict__ Ab, ushort_t* __restrict__ Bb,
    float* __restrict__ partials)
{
    const int tid  = threadIdx.x;
    const int lane = tid & 63;
    const int wv   = tid >> 6;
    const int sl   = lane & 15;
    const int rowg = blockIdx.x * 16 + wv * 4 + (lane >> 4);   // 0..65535
    const bool isPre = rowg < TB * NP;                         // block-uniform
    const int m = isPre ? rowg : rowg - TB * NP;
    const int b = m >> 11;
    const int r = m & 2047;

    const float4* srcRow = (const float4*)((isPre ? pre : post) + (size_t)m * TT);
    const float4 u0 = srcRow[4 * sl + 0];   // t = 16sl + 0..3
    const float4 u1 = srcRow[4 * sl + 1];   // t = 16sl + 4..7
    const float4 u2 = srcRow[4 * sl + 2];   // t = 16sl + 8..11
    const float4 u3 = srcRow[4 * sl + 3];   // t = 16sl + 12..15

    float cnt = ((u0.x + u0.y) + (u0.z + u0.w)) + ((u1.x + u1.y) + (u1.z + u1.w))
              + ((u2.x + u2.y) + (u2.z + u2.w)) + ((u3.x + u3.y) + (u3.z + u3.w));

    // ---- fast-decay trace: fold16 -> scan -> exclusive carry ----
    const float Bf = foldc4(foldc4(foldc4(foldc4(0.f, u0, DF1), u1, DF1),
                                   u2, DF1), u3, DF1);
    const float bfi = scan16(Bf, DF16, DF32, DF64, DF128, sl);
    float ef = __shfl_up(bfi, 1, 64);
    if (sl == 0) ef = 0.f;

    ushort_t* oA = (isPre ? Ab : Bb) + (size_t)r * KT + b * TT + 16 * sl;

    if (isPre) {
        float x = ef;
        const float4 t0 = expand4c(x, u0, DF1);
        const float4 t1 = expand4c(x, u1, DF1);
        const float4 t2 = expand4c(x, u2, DF1);
        const float4 t3 = expand4c(x, u3, DF1);
        *(uint4*)(oA)          = uint4{pack2(t0.x, t0.y), pack2(t0.z, t0.w),
                                       pack2(t1.x, t1.y), pack2(t1.z, t1.w)};
        *(uint4*)(oA + 8)      = uint4{pack2(t2.x, t2.y), pack2(t2.z, t2.w),
                                       pack2(t3.x, t3.y), pack2(t3.z, t3.w)};
        *(uint4*)(oA + KH)     = uint4{spk2(u0.x, u0.y), spk2(u0.z, u0.w),
                                       spk2(u1.x, u1.y), spk2(u1.z, u1.w)};
        *(uint4*)(oA + KH + 8) = uint4{spk2(u2.x, u2.y), spk2(u2.z, u2.w),
                                       spk2(u3.x, u3.y), spk2(u3.z, u3.w)};
    } else {
        // ---- slow (triplet) trace: second scan ----
        const float Bx = foldc4(foldc4(foldc4(foldc4(0.f, u0, DX1), u1, DX1),
                                       u2, DX1), u3, DX1);
        const float bxi = scan16(Bx, DX16, DX32, DX64, DX128, sl);
        float ex = __shfl_up(bxi, 1, 64);
        if (sl == 0) ex = 0.f;

        float xf = ef, xx = ex;
        const float4 tf0 = expand4c(xf, u0, DF1);
        const float4 tx0 = expand4c(xx, u0, DX1);
        const float4 tf1 = expand4c(xf, u1, DF1);
        const float4 tx1 = expand4c(xx, u1, DX1);
        const float4 tf2 = expand4c(xf, u2, DF1);
        const float4 tx2 = expand4c(xx, u2, DX1);
        const float4 tf3 = expand4c(xf, u3, DF1);
        const float4 tx3 = expand4c(xx, u3, DX1);

        const float Ap = *mApP;
        const float Am = *mAmP;
        auto av2 = [&](float sa, float ta, float sb, float tb) -> unsigned {
            unsigned lo  = (sa != 0.f) ? bf1(fmaf(0.0065f, ta, Ap)) : 0u;
            unsigned hi2 = (sb != 0.f) ? bf1(fmaf(0.0065f, tb, Ap)) : 0u;
            return lo | (hi2 << 16);
        };
        *(uint4*)(oA)          = uint4{av2(u0.x, tx0.x, u0.y, tx0.y),
                                       av2(u0.z, tx0.z, u0.w, tx0.w),
                                       av2(u1.x, tx1.x, u1.y, tx1.y),
                                       av2(u1.z, tx1.z, u1.w, tx1.w)};
        *(uint4*)(oA + 8)      = uint4{av2(u2.x, tx2.x, u2.y, tx2.y),
                                       av2(u2.z, tx2.z, u2.w, tx2.w),
                                       av2(u3.x, tx3.x, u3.y, tx3.y),
                                       av2(u3.z, tx3.z, u3.w, tx3.w)};
        *(uint4*)(oA + KH)     = uint4{pack2(-Am * tf0.x, -Am * tf0.y),
                                       pack2(-Am * tf0.z, -Am * tf0.w),
                                       pack2(-Am * tf1.x, -Am * tf1.y),
                                       pack2(-Am * tf1.z, -Am * tf1.w)};
        *(uint4*)(oA + KH + 8) = uint4{pack2(-Am * tf2.x, -Am * tf2.y),
                                       pack2(-Am * tf2.z, -Am * tf2.w),
                                       pack2(-Am * tf3.x, -Am * tf3.y),
                                       pack2(-Am * tf3.z, -Am * tf3.w)};
    }

    #pragma unroll
    for (int off = 32; off > 0; off >>= 1)
        cnt += __shfl_down(cnt, off, 64);
    __shared__ float wsum[4];
    if (lane == 0) wsum[wv] = cnt;
    __syncthreads();
    if (tid == 0)
        partials[blockIdx.x] = (wsum[0] + wsum[1]) + (wsum[2] + wsum[3]);
}

// ---------------------------------------------------------------------------
// Stage 2 (r9 verbatim, proven 199.3): split-K=2 GEMM (BK=64, double-buffered
// global_load_lds prefetch, XOR LDS swizzle, XCD-patched grid of 512 =
// 2 blocks/CU; 904 TF effective). Block 0 also reduces the 4096 spike-count
// partials -> scaleBuf. z=0 -> d_out, z=1 -> ws.
// ---------------------------------------------------------------------------
__device__ __forceinline__ void async16(const ushort_t* g, ushort_t* l) {
    __builtin_amdgcn_global_load_lds(
        (const __attribute__((address_space(1))) unsigned int*)g,
        (__attribute__((address_space(3))) unsigned int*)l,
        16, 0, 0);
}

__global__ __launch_bounds__(256, 2) void gemm_split(
    const ushort_t* __restrict__ Ab, const ushort_t* __restrict__ Bb,
    const float* __restrict__ sp, float* __restrict__ scaleBuf,
    float* __restrict__ P0, float* __restrict__ P1)
{
    __shared__ ushort_t As[2][128 * 64];
    __shared__ ushort_t Bs[2][128 * 64];
    __shared__ float red[4];

    const int tid  = threadIdx.x;
    const int lane = tid & 63;
    const int wv   = tid >> 6;
    const int wr   = wv >> 1;
    const int wc   = wv & 1;
    const int quad = lane >> 4;
    const int m16  = lane & 15;

    // block 0: reduce the 4096 spike-count partials -> scale
    if (blockIdx.x == 0) {
        float v = 0.f;
        #pragma unroll
        for (int i = 0; i < 16; ++i) v += sp[tid + i * 256];
        #pragma unroll
        for (int off = 32; off > 0; off >>= 1)
            v += __shfl_down(v, off, 64);
        if (lane == 0) red[wv] = v;
        __syncthreads();
        if (tid == 0) {
            float s = (red[0] + red[1]) + (red[2] + red[3]);
            scaleBuf[0] = sqrtf(0.1f / (s * (1.0f / 4096.0f) + 1e-6f));
        }
    }

    // XCD swizzle: id&7 = XCD; fixed 4x8 (p,q) patch per XCD, z inner
    const int id  = blockIdx.x;
    const int xcd = id & 7;
    const int j5  = id >> 3;          // 0..63
    const int z   = j5 & 1;
    const int t   = j5 >> 1;          // 0..31
    const int pt  = ((xcd >> 1) << 2) + (t >> 3);   // 0..15
    const int qt  = ((xcd & 1) << 3) + (t & 7);     // 0..15

    const int p0 = pt * 128;
    const int q0 = qt * 128;
    const int kbase = z * (KT / 2);
    const int ldsbase = wv * 512;     // elements; wave-uniform

    const ushort_t* gaP[4];
    const ushort_t* gbP[4];
    #pragma unroll
    for (int rr = 0; rr < 4; ++rr) {
        const int c   = rr * 256 + tid;
        const int row = c >> 3;
        const int kk8 = (c & 7) ^ (row & 7);
        gaP[rr] = Ab + (size_t)(p0 + row) * KT + kbase + kk8 * 8;
        gbP[rr] = Bb + (size_t)(q0 + row) * KT + kbase + kk8 * 8;
    }

    f32x4 acc[4][4] = {};

    auto stageF = [&](int buf) {
        #pragma unroll
        for (int rr = 0; rr < 4; ++rr) {
            async16(gaP[rr], &As[buf][rr * 2048 + ldsbase]);
            async16(gbP[rr], &Bs[buf][rr * 2048 + ldsbase]);
            gaP[rr] += 64;
            gbP[rr] += 64;
        }
    };
    auto computeF = [&](int buf) {
        #pragma unroll
        for (int ks = 0; ks < 2; ++ks) {
            bf16x8 af[4], bfr[4];
            #pragma unroll
            for (int i = 0; i < 4; ++i) {
                const int row  = wr * 64 + i * 16 + m16;
                const int slot = (ks * 4 + quad) ^ (row & 7);
                af[i] = *(const bf16x8*)&As[buf][row * 64 + slot * 8];
            }
            #pragma unroll
            for (int jj = 0; jj < 4; ++jj) {
                const int row  = wc * 64 + jj * 16 + m16;
                const int slot = (ks * 4 + quad) ^ (row & 7);
                bfr[jj] = *(const bf16x8*)&Bs[buf][row * 64 + slot * 8];
            }
            #pragma unroll
            for (int i = 0; i < 4; ++i)
                #pragma unroll
                for (int jj = 0; jj < 4; ++jj)
                    acc[i][jj] = __builtin_amdgcn_mfma_f32_16x16x32_bf16(
                        af[i], bfr[jj], acc[i][jj], 0, 0, 0);
        }
    };

    constexpr int NIT = (KT / 2) / 64;   // 64 k-chunks, 32 double-iters
    stageF(0);
    for (int kt2 = 0; kt2 < NIT / 2; ++kt2) {
        __syncthreads();
        stageF(1);
        computeF(0);
        __syncthreads();
        if (kt2 + 1 < NIT / 2)
            stageF(0);
        computeF(1);
    }

    float* P = z ? P1 : P0;
    #pragma unroll
    for (int i = 0; i < 4; ++i) {
        const int prow = p0 + wr * 64 + i * 16 + quad * 4;
        #pragma unroll
        for (int jj = 0; jj < 4; ++jj) {
            const int qcol = q0 + wc * 64 + jj * 16 + m16;
            #pragma unroll
            for (int r2 = 0; r2 < 4; ++r2)
                P[(size_t)(prow + r2) * NQ + qcol] = acc[i][jj][r2];
        }
    }
}

// ---------------------------------------------------------------------------
// Stage 3 (r9 verbatim): Out = clip(W + scale*(P0+P1), -2, 2); P0 in d_out.
// ---------------------------------------------------------------------------
__global__ __launch_bounds__(256) void merge_out(
    const float* __restrict__ W, const float* __restrict__ P1,
    const float* __restrict__ scaleBuf, float* __restrict__ Out)
{
    const float scale = scaleBuf[0];
    const size_t i4 = (size_t)blockIdx.x * 256 + threadIdx.x;
    float4 w = ((const float4*)W)[i4];
    float4 a = ((const float4*)Out)[i4];
    float4 c = ((const float4*)P1)[i4];
    float4 o;
    o.x = fminf(fmaxf(fmaf(scale, a.x + c.x, w.x), -2.f), 2.f);
    o.y = fminf(fmaxf(fmaf(scale, a.y + c.y, w.y), -2.f), 2.f);
    o.z = fminf(fmaxf(fmaf(scale, a.z + c.z, w.z), -2.f), 2.f);
    o.w = fminf(fmaxf(fmaf(scale, a.w + c.w, w.w), -2.f), 2.f);
    ((float4*)Out)[i4] = o;
}

extern "C" void kernel_launch(void* const* d_in, const int* in_sizes, int n_in,
                              void* d_out, int out_size, void* d_ws, size_t ws_size,
                              hipStream_t stream) {
    const float* pre  = (const float*)d_in[0];
    const float* post = (const float*)d_in[1];
    const float* W    = (const float*)d_in[2];
    const float* mAp  = (const float*)d_in[3];
    const float* mAm  = (const float*)d_in[4];
    float* out = (float*)d_out;

    char* ws = (char*)d_ws;
    float* partials = (float*)ws;                                    // 16 KB (4096 slots)
    float* scaleBuf = (float*)(ws + 16384);
    ushort_t* Ab = (ushort_t*)(ws + 32768);                          // 33.6 MB
    ushort_t* Bb = (ushort_t*)(ws + 32768 + (size_t)NP * KT * 2);    // 33.6 MB
    float* P1    = (float*)(ws + 32768 + 2 * (size_t)NP * KT * 2);   // 16.8 MB

    stage_traces<<<dim3((TB * NP + TB * NQ) / 16), dim3(256), 0, stream>>>(
        pre, post, mAp, mAm, Ab, Bb, partials);

    gemm_split<<<dim3(512), dim3(256), 0, stream>>>(
        Ab, Bb, partials, scaleBuf, out, P1);

    merge_out<<<dim3(NP * NQ / 1024), dim3(256), 0, stream>>>(
        W, P1, scaleBuf, out);
}